// Round 1
// baseline (1329.647 us; speedup 1.0000x reference)
//
#include <hip/hip_runtime.h>
#include <math.h>

#define TEMP_F   0.5f
#define ALPHA_F  1.0f
#define BETA_F   5.5f
#define GAMMA_F  5.0f
#define N_IMG    400
#define D_DIM    512
#define C_CLS    1000
#define M_SUP    16000

// ---------- helpers ----------
__device__ __forceinline__ unsigned encf(float f) {
    unsigned u = __float_as_uint(f);
    return (u & 0x80000000u) ? ~u : (u | 0x80000000u);
}
__device__ __forceinline__ float decf(unsigned u) {
    return (u & 0x80000000u) ? __uint_as_float(u & 0x7FFFFFFFu) : __uint_as_float(~u);
}

__device__ __forceinline__ float block_reduce_sum(float v) {
    __shared__ float red[4];
    #pragma unroll
    for (int o = 32; o > 0; o >>= 1) v += __shfl_down(v, o, 64);
    int w = threadIdx.x >> 6, l = threadIdx.x & 63;
    __syncthreads();
    if (l == 0) red[w] = v;
    __syncthreads();
    float r = red[0];
    int nw = blockDim.x >> 6;
    for (int i = 1; i < nw; ++i) r += red[i];
    return r;
}

__device__ __forceinline__ float block_reduce_max(float v) {
    __shared__ float redm[4];
    #pragma unroll
    for (int o = 32; o > 0; o >>= 1) v = fmaxf(v, __shfl_down(v, o, 64));
    int w = threadIdx.x >> 6, l = threadIdx.x & 63;
    __syncthreads();
    if (l == 0) redm[w] = v;
    __syncthreads();
    float r = redm[0];
    int nw = blockDim.x >> 6;
    for (int i = 1; i < nw; ++i) r = fmaxf(r, redm[i]);
    return r;
}

// ---------- kernels ----------
__global__ void init_mm_k(unsigned* mm) {
    // [0]=klmin [1]=klmax [2]=nkmin [3]=nkmax (encoded)
    mm[0] = encf(INFINITY);
    mm[1] = encf(-INFINITY);
    mm[2] = encf(INFINITY);
    mm[3] = encf(-INFINITY);
}

__global__ void normalize_rows_k(const float* __restrict__ src, float* __restrict__ dst, int cols) {
    int row = blockIdx.x;
    const float* s = src + (long)row * cols;
    float* d = dst + (long)row * cols;
    float ss = 0.f;
    for (int c = threadIdx.x; c < cols; c += blockDim.x) { float v = s[c]; ss += v * v; }
    float tot = block_reduce_sum(ss);
    float inv = 1.0f / fmaxf(sqrtf(tot), 1e-12f);
    for (int c = threadIdx.x; c < cols; c += blockDim.x) d[c] = s[c] * inv;
}

// C[i,j] = alpha * sum_k A[i*sai + k*sak] * B[j*sbj + k*sbk]
// 128x128 tile, BK=16, 256 threads, 8x8 per thread.
template<bool AKC, bool BKC>
__global__ __launch_bounds__(256) void gemm128(
    const float* __restrict__ A, const float* __restrict__ B, float* __restrict__ Cm,
    int I, int J, int K, long sai, long sak, long sbj, long sbk, long ldc, float alpha)
{
    __shared__ __align__(16) float As[16][132];
    __shared__ __align__(16) float Bs[16][132];
    const int tid = threadIdx.x;
    const int i0 = blockIdx.y * 128;
    const int j0 = blockIdx.x * 128;
    const int tm = (tid & 15) * 4;
    const int tn = (tid >> 4) * 4;

    float acc[2][2][4][4] = {};

    for (int k0 = 0; k0 < K; k0 += 16) {
        // stage A
        if (AKC) {
            #pragma unroll
            for (int r = 0; r < 8; ++r) {
                int idx = tid * 8 + r;
                int i = idx >> 4, k = idx & 15;
                int gi = i0 + i, gk = k0 + k;
                As[k][i] = (gi < I && gk < K) ? A[(long)gi * sai + (long)gk * sak] : 0.f;
            }
        } else {
            #pragma unroll
            for (int r = 0; r < 8; ++r) {
                int idx = tid + 256 * r;
                int i = idx & 127, k = idx >> 7;
                int gi = i0 + i, gk = k0 + k;
                As[k][i] = (gi < I && gk < K) ? A[(long)gi * sai + (long)gk * sak] : 0.f;
            }
        }
        // stage B
        if (BKC) {
            #pragma unroll
            for (int r = 0; r < 8; ++r) {
                int idx = tid * 8 + r;
                int j = idx >> 4, k = idx & 15;
                int gj = j0 + j, gk = k0 + k;
                Bs[k][j] = (gj < J && gk < K) ? B[(long)gj * sbj + (long)gk * sbk] : 0.f;
            }
        } else {
            #pragma unroll
            for (int r = 0; r < 8; ++r) {
                int idx = tid + 256 * r;
                int j = idx & 127, k = idx >> 7;
                int gj = j0 + j, gk = k0 + k;
                Bs[k][j] = (gj < J && gk < K) ? B[(long)gj * sbj + (long)gk * sbk] : 0.f;
            }
        }
        __syncthreads();

        #pragma unroll
        for (int k = 0; k < 16; ++k) {
            float4 a0 = *(const float4*)(&As[k][tm]);
            float4 a1 = *(const float4*)(&As[k][tm + 64]);
            float4 b0 = *(const float4*)(&Bs[k][tn]);
            float4 b1 = *(const float4*)(&Bs[k][tn + 64]);
            float av[2][4] = {{a0.x, a0.y, a0.z, a0.w}, {a1.x, a1.y, a1.z, a1.w}};
            float bv[2][4] = {{b0.x, b0.y, b0.z, b0.w}, {b1.x, b1.y, b1.z, b1.w}};
            #pragma unroll
            for (int ih = 0; ih < 2; ++ih)
                #pragma unroll
                for (int jh = 0; jh < 2; ++jh)
                    #pragma unroll
                    for (int x = 0; x < 4; ++x)
                        #pragma unroll
                        for (int y = 0; y < 4; ++y)
                            acc[ih][jh][x][y] = fmaf(av[ih][x], bv[jh][y], acc[ih][jh][x][y]);
        }
        __syncthreads();
    }

    #pragma unroll
    for (int ih = 0; ih < 2; ++ih) {
        #pragma unroll
        for (int x = 0; x < 4; ++x) {
            int gi = i0 + ih * 64 + tm + x;
            if (gi >= I) continue;
            #pragma unroll
            for (int jh = 0; jh < 2; ++jh) {
                #pragma unroll
                for (int y = 0; y < 4; ++y) {
                    int gj = j0 + jh * 64 + tn + y;
                    if (gj < J) Cm[(long)gi * ldc + gj] = alpha * acc[ih][jh][x][y];
                }
            }
        }
    }
}

// per-row logsumexp of t [rows x C_CLS]
__global__ void row_lse_k(const float* __restrict__ t, float* __restrict__ lse) {
    int row = blockIdx.x;
    const float* r = t + (long)row * C_CLS;
    float mx = -INFINITY;
    for (int c = threadIdx.x; c < C_CLS; c += blockDim.x) mx = fmaxf(mx, r[c]);
    mx = block_reduce_max(mx);
    float se = 0.f;
    for (int c = threadIdx.x; c < C_CLS; c += blockDim.x) se += expf(r[c] - mx);
    se = block_reduce_sum(se);
    if (threadIdx.x == 0) lse[row] = mx + logf(se);
}

// test softmax: logits = 2*dot; p, entropy = sum p log p
__global__ void test_softmax_k(const float* __restrict__ dot, float* __restrict__ p,
                               float* __restrict__ ent) {
    int n = blockIdx.x;
    const float* dr = dot + (long)n * C_CLS;
    float* pr = p + (long)n * C_CLS;
    float mx = -INFINITY;
    for (int c = threadIdx.x; c < C_CLS; c += blockDim.x) mx = fmaxf(mx, 2.f * dr[c]);
    mx = block_reduce_max(mx);
    float se = 0.f;
    for (int c = threadIdx.x; c < C_CLS; c += blockDim.x) se += expf(2.f * dr[c] - mx);
    se = block_reduce_sum(se);
    float logsum = mx + logf(se);
    float e = 0.f;
    for (int c = threadIdx.x; c < C_CLS; c += blockDim.x) {
        float lp = 2.f * dr[c] - logsum;
        float pv = expf(lp);
        pr[c] = pv;
        e += pv * lp;
    }
    e = block_reduce_sum(e);
    if (threadIdx.x == 0) ent[n] = e;
}

// kl[n,m] = ent[n] - A2[n,m] + lse[m]; global min/max
__global__ void minmax_kl_k(const float* __restrict__ A2, const float* __restrict__ ent,
                            const float* __restrict__ lse, unsigned* mm) {
    int n = blockIdx.y;
    float e = ent[n];
    float lmin = INFINITY, lmax = -INFINITY;
    for (int m = blockIdx.x * blockDim.x + threadIdx.x; m < M_SUP; m += gridDim.x * blockDim.x) {
        float kl = e - A2[(long)n * M_SUP + m] + lse[m];
        lmin = fminf(lmin, kl);
        lmax = fmaxf(lmax, kl);
    }
    __shared__ unsigned smin, smax;
    if (threadIdx.x == 0) { smin = encf(INFINITY); smax = encf(-INFINITY); }
    __syncthreads();
    atomicMin(&smin, encf(lmin));
    atomicMax(&smax, encf(lmax));
    __syncthreads();
    if (threadIdx.x == 0) { atomicMin(&mm[0], smin); atomicMax(&mm[1], smax); }
}

__global__ void minmax_nk_k(const float* __restrict__ nk, unsigned* mm) {
    int n = blockIdx.y;
    float lmin = INFINITY, lmax = -INFINITY;
    for (int m = blockIdx.x * blockDim.x + threadIdx.x; m < M_SUP; m += gridDim.x * blockDim.x) {
        float v = nk[(long)n * M_SUP + m];
        lmin = fminf(lmin, v);
        lmax = fmaxf(lmax, v);
    }
    __shared__ unsigned smin, smax;
    if (threadIdx.x == 0) { smin = encf(INFINITY); smax = encf(-INFINITY); }
    __syncthreads();
    atomicMin(&smin, encf(lmin));
    atomicMax(&smax, encf(lmax));
    __syncthreads();
    if (threadIdx.x == 0) { atomicMin(&mm[2], smin); atomicMax(&mm[3], smax); }
}

__global__ __launch_bounds__(256) void final_k(
    const float* __restrict__ dot, const float* __restrict__ A2, const float* __restrict__ nk,
    const int* __restrict__ labels, const unsigned* __restrict__ mm,
    const float* __restrict__ ent, const float* __restrict__ lse, float* __restrict__ out)
{
    int n = blockIdx.x;
    __shared__ float bins[C_CLS];
    for (int c = threadIdx.x; c < C_CLS; c += 256) bins[c] = 0.f;
    __syncthreads();
    float klmin = decf(mm[0]), klmax = decf(mm[1]);
    float nkmin = decf(mm[2]), nkmax = decf(mm[3]);
    float ratio = (nkmax - nkmin) / (klmax - klmin);
    float e = ent[n];
    for (int m = threadIdx.x; m < M_SUP; m += 256) {
        float a2 = A2[(long)n * M_SUP + m];
        float v  = nk[(long)n * M_SUP + m];
        float kl = e - a2 + lse[m];
        float y  = (kl - klmin) * ratio + nkmin;   // scaled neg_aff
        float contrib = -GAMMA_F * y + ALPHA_F * expf(BETA_F * (v - 1.0f));
        atomicAdd(&bins[labels[m]], contrib);
    }
    __syncthreads();
    for (int c = threadIdx.x; c < C_CLS; c += 256)
        out[(long)n * C_CLS + c] = 100.f * dot[(long)n * C_CLS + c] + bins[c];
}

// ---------- launch ----------
extern "C" void kernel_launch(void* const* d_in, const int* in_sizes, int n_in,
                              void* d_out, int out_size, void* d_ws, size_t ws_size,
                              hipStream_t stream) {
    const float* image_features = (const float*)d_in[0];   // [N, D]
    const float* text_embeds    = (const float*)d_in[1];   // [C, D]
    const float* support_feats  = (const float*)d_in[2];   // [D, M]
    const int*   support_labels = (const int*)d_in[3];     // [M]
    float* out = (float*)d_out;

    float* fws = (float*)d_ws;
    size_t off = 0;
    auto alloc = [&](size_t nfloat) {
        float* p = fws + off;
        off += (nfloat + 63) & ~(size_t)63;
        return p;
    };
    float* Tn   = alloc((size_t)C_CLS * D_DIM);   // normalized text [C, D]
    float* img  = alloc((size_t)N_IMG * D_DIM);   // normalized image [N, D]
    float* t    = alloc((size_t)M_SUP * C_CLS);   // train logits [M, C] (already /TEMP)
    float* lse  = alloc((size_t)M_SUP);           // per-row lse of t
    float* dot  = alloc((size_t)N_IMG * C_CLS);   // img @ Tn^T (unscaled)
    float* p    = alloc((size_t)N_IMG * C_CLS);   // test softmax probs
    float* ent  = alloc((size_t)N_IMG);           // entropy term per row
    float* A2   = alloc((size_t)N_IMG * M_SUP);   // p @ t^T
    float* nk   = alloc((size_t)N_IMG * M_SUP);   // img @ S
    unsigned* mm = (unsigned*)alloc(64);          // encoded min/max scalars

    init_mm_k<<<1, 1, 0, stream>>>(mm);
    normalize_rows_k<<<C_CLS, 256, 0, stream>>>(text_embeds, Tn, D_DIM);
    normalize_rows_k<<<N_IMG, 256, 0, stream>>>(image_features, img, D_DIM);

    // GEMM1: t[m,c] = 2 * sum_d S[d,m] * Tn[c,d]   (I=M, J=C, K=D)
    gemm128<false, true><<<dim3(8, 125), 256, 0, stream>>>(
        support_feats, Tn, t, M_SUP, C_CLS, D_DIM,
        1L, (long)M_SUP, (long)D_DIM, 1L, (long)C_CLS, 2.0f);

    row_lse_k<<<M_SUP, 256, 0, stream>>>(t, lse);

    // GEMM0: dot[n,c] = sum_d img[n,d] * Tn[c,d]   (I=N, J=C, K=D)
    gemm128<true, true><<<dim3(8, 4), 256, 0, stream>>>(
        img, Tn, dot, N_IMG, C_CLS, D_DIM,
        (long)D_DIM, 1L, (long)D_DIM, 1L, (long)C_CLS, 1.0f);

    test_softmax_k<<<N_IMG, 256, 0, stream>>>(dot, p, ent);

    // GEMM2: A2[n,m] = sum_c p[n,c] * t[m,c]   (I=N, J=M, K=C)
    gemm128<true, true><<<dim3(125, 4), 256, 0, stream>>>(
        p, t, A2, N_IMG, M_SUP, C_CLS,
        (long)C_CLS, 1L, (long)C_CLS, 1L, (long)M_SUP, 1.0f);

    // GEMM3: nk[n,m] = sum_d img[n,d] * S[d,m]   (I=N, J=M, K=D)
    gemm128<true, false><<<dim3(125, 4), 256, 0, stream>>>(
        img, support_feats, nk, N_IMG, M_SUP, D_DIM,
        (long)D_DIM, 1L, 1L, (long)M_SUP, (long)M_SUP, 1.0f);

    minmax_kl_k<<<dim3(8, N_IMG), 256, 0, stream>>>(A2, ent, lse, mm);
    minmax_nk_k<<<dim3(8, N_IMG), 256, 0, stream>>>(nk, mm);

    final_k<<<N_IMG, 256, 0, stream>>>(dot, A2, nk, support_labels, mm, ent, lse, out);
}

// Round 2
// 441.441 us; speedup vs baseline: 3.0121x; 3.0121x over previous
//
#include <hip/hip_runtime.h>
#include <math.h>

#define TEMP_F   0.5f
#define ALPHA_F  1.0f
#define BETA_F   5.5f
#define GAMMA_F  5.0f
#define N_IMG    400
#define D_DIM    512
#define C_CLS    1000
#define C_PAD    1024
#define M_SUP    16000

typedef __attribute__((ext_vector_type(8))) short short8;
typedef __attribute__((ext_vector_type(4))) float f32x4;

// ---------- helpers ----------
__device__ __forceinline__ short f2bf(float f) {
    unsigned u = __float_as_uint(f);
    unsigned r = (u + 0x7fffu + ((u >> 16) & 1u)) >> 16;
    return (short)r;
}
__device__ __forceinline__ float bf2f(short s) {
    return __uint_as_float(((unsigned)(unsigned short)s) << 16);
}
__device__ __forceinline__ unsigned encf(float f) {
    unsigned u = __float_as_uint(f);
    return (u & 0x80000000u) ? ~u : (u | 0x80000000u);
}
__device__ __forceinline__ float decf(unsigned u) {
    return (u & 0x80000000u) ? __uint_as_float(u & 0x7FFFFFFFu) : __uint_as_float(~u);
}

__device__ __forceinline__ float block_reduce_sum(float v) {
    __shared__ float red[4];
    #pragma unroll
    for (int o = 32; o > 0; o >>= 1) v += __shfl_down(v, o, 64);
    int w = threadIdx.x >> 6, l = threadIdx.x & 63;
    __syncthreads();
    if (l == 0) red[w] = v;
    __syncthreads();
    float r = red[0];
    int nw = blockDim.x >> 6;
    for (int i = 1; i < nw; ++i) r += red[i];
    return r;
}

__device__ __forceinline__ float block_reduce_max(float v) {
    __shared__ float redm[4];
    #pragma unroll
    for (int o = 32; o > 0; o >>= 1) v = fmaxf(v, __shfl_down(v, o, 64));
    int w = threadIdx.x >> 6, l = threadIdx.x & 63;
    __syncthreads();
    if (l == 0) redm[w] = v;
    __syncthreads();
    float r = redm[0];
    int nw = blockDim.x >> 6;
    for (int i = 1; i < nw; ++i) r = fmaxf(r, redm[i]);
    return r;
}

__device__ __forceinline__ void gload_lds16(const void* g, void* l) {
    __builtin_amdgcn_global_load_lds(
        (const __attribute__((address_space(1))) unsigned int*)g,
        (__attribute__((address_space(3))) unsigned int*)l, 16, 0, 0);
}

// ---------- kernels ----------
__global__ void init_mm_k(unsigned* mm) {
    mm[0] = encf(INFINITY);   // klmin
    mm[1] = encf(-INFINITY);  // klmax
    mm[2] = encf(INFINITY);   // nkmin
    mm[3] = encf(-INFINITY);  // nkmax
}

// normalize rows of src [rows x 512] fp32 -> dst bf16 [rows x 512]
__global__ void normalize_rows_k(const float* __restrict__ src, short* __restrict__ dst) {
    int row = blockIdx.x;
    const float* s = src + (long)row * D_DIM;
    short* d = dst + (long)row * D_DIM;
    float ss = 0.f;
    for (int c = threadIdx.x; c < D_DIM; c += blockDim.x) { float v = s[c]; ss += v * v; }
    float tot = block_reduce_sum(ss);
    float inv = 1.0f / fmaxf(sqrtf(tot), 1e-12f);
    for (int c = threadIdx.x; c < D_DIM; c += blockDim.x) d[c] = f2bf(s[c] * inv);
}

// S [D_DIM x M_SUP] fp32 -> Sb [M_SUP x D_DIM] bf16
__global__ void transpose_bf16_k(const float* __restrict__ S, short* __restrict__ Sb) {
    __shared__ float tile[32][33];
    int m0 = blockIdx.x * 32, d0 = blockIdx.y * 32;
    int tx = threadIdx.x & 31, ty = threadIdx.x >> 5;  // 32 x 8
    #pragma unroll
    for (int r = 0; r < 32; r += 8)
        tile[ty + r][tx] = S[(long)(d0 + ty + r) * M_SUP + m0 + tx];
    __syncthreads();
    #pragma unroll
    for (int r = 0; r < 32; r += 8)
        Sb[(long)(m0 + ty + r) * D_DIM + d0 + tx] = f2bf(tile[tx][ty + r]);
}

// bf16 MFMA GEMM: C[i,j] = alpha * sum_k A[i,k]*B[j,k], A [I x lda], B [rows x ldb]
// 128x128 tile, BK=32, 256 threads (4 waves), 4x4 16x16x32 MFMAs per wave.
template<bool OUT_BF16>
__global__ __launch_bounds__(256) void mfma_gemm(
    const short* __restrict__ A, const short* __restrict__ B, void* __restrict__ Cm,
    int I, int Jclamp, int Jout, int K, long lda, long ldb, long ldc, float alpha)
{
    __shared__ short As[128 * 32];
    __shared__ short Bs[128 * 32];
    const int tid = threadIdx.x;
    const int wave = tid >> 6;
    const int lane = tid & 63;
    const int i0 = blockIdx.y * 128;
    const int j0 = blockIdx.x * 128;

    const int srow = wave * 16 + (lane >> 2);  // staging row within 64-row group
    const int skk  = (lane & 3) * 8;           // staging k offset (bf16 elems)

    const int wm = (wave & 1) * 64;
    const int wn = (wave >> 1) * 64;
    const int fr = lane & 15;   // fragment row/col
    const int fq = lane >> 4;   // quad

    f32x4 acc[4][4] = {};

    for (int k0 = 0; k0 < K; k0 += 32) {
        #pragma unroll
        for (int q = 0; q < 2; ++q) {
            int gi = i0 + q * 64 + srow; if (gi > I - 1) gi = I - 1;
            gload_lds16(A + (long)gi * lda + k0 + skk, As + q * 2048 + wave * 512);
        }
        #pragma unroll
        for (int q = 0; q < 2; ++q) {
            int gj = j0 + q * 64 + srow; if (gj > Jclamp - 1) gj = Jclamp - 1;
            gload_lds16(B + (long)gj * ldb + k0 + skk, Bs + q * 2048 + wave * 512);
        }
        __syncthreads();

        short8 af[4], bf[4];
        #pragma unroll
        for (int mi = 0; mi < 4; ++mi)
            af[mi] = *(const short8*)(As + (wm + mi * 16 + fr) * 32 + fq * 8);
        #pragma unroll
        for (int ni = 0; ni < 4; ++ni)
            bf[ni] = *(const short8*)(Bs + (wn + ni * 16 + fr) * 32 + fq * 8);
        #pragma unroll
        for (int mi = 0; mi < 4; ++mi)
            #pragma unroll
            for (int ni = 0; ni < 4; ++ni)
                acc[mi][ni] = __builtin_amdgcn_mfma_f32_16x16x32_bf16(
                    af[mi], bf[ni], acc[mi][ni], 0, 0, 0);
        __syncthreads();
    }

    #pragma unroll
    for (int mi = 0; mi < 4; ++mi) {
        #pragma unroll
        for (int ni = 0; ni < 4; ++ni) {
            int gj = j0 + wn + ni * 16 + fr;
            if (gj >= Jout) continue;
            #pragma unroll
            for (int t = 0; t < 4; ++t) {
                int gi = i0 + wm + mi * 16 + fq * 4 + t;
                if (gi < I) {
                    float v = alpha * acc[mi][ni][t];
                    if (OUT_BF16) ((short*)Cm)[(long)gi * ldc + gj] = f2bf(v);
                    else          ((float*)Cm)[(long)gi * ldc + gj] = v;
                }
            }
        }
    }
}

// per-row logsumexp over tb bf16 [M_SUP x C_PAD], cols < C_CLS
__global__ void row_lse_k(const short* __restrict__ t, float* __restrict__ lse) {
    int row = blockIdx.x;
    const short* r = t + (long)row * C_PAD;
    float mx = -INFINITY;
    for (int c = threadIdx.x; c < C_CLS; c += blockDim.x) mx = fmaxf(mx, bf2f(r[c]));
    mx = block_reduce_max(mx);
    float se = 0.f;
    for (int c = threadIdx.x; c < C_CLS; c += blockDim.x) se += expf(bf2f(r[c]) - mx);
    se = block_reduce_sum(se);
    if (threadIdx.x == 0) lse[row] = mx + logf(se);
}

// test softmax: logits = 2*dot; writes p as bf16 (pad zeros), entropy
__global__ void test_softmax_k(const float* __restrict__ dot, short* __restrict__ p,
                               float* __restrict__ ent) {
    int n = blockIdx.x;
    const float* dr = dot + (long)n * C_PAD;
    short* pr = p + (long)n * C_PAD;
    float mx = -INFINITY;
    for (int c = threadIdx.x; c < C_CLS; c += blockDim.x) mx = fmaxf(mx, 2.f * dr[c]);
    mx = block_reduce_max(mx);
    float se = 0.f;
    for (int c = threadIdx.x; c < C_CLS; c += blockDim.x) se += expf(2.f * dr[c] - mx);
    se = block_reduce_sum(se);
    float logsum = mx + logf(se);
    float e = 0.f;
    for (int c = threadIdx.x; c < C_PAD; c += blockDim.x) {
        if (c < C_CLS) {
            float lp = 2.f * dr[c] - logsum;
            float pv = expf(lp);
            pr[c] = f2bf(pv);
            e += pv * lp;
        } else {
            pr[c] = 0;
        }
    }
    e = block_reduce_sum(e);
    if (threadIdx.x == 0) ent[n] = e;
}

__global__ void minmax_kl_k(const float* __restrict__ A2, const float* __restrict__ ent,
                            const float* __restrict__ lse, unsigned* mm) {
    int n = blockIdx.y;
    float e = ent[n];
    float lmin = INFINITY, lmax = -INFINITY;
    for (int m = blockIdx.x * blockDim.x + threadIdx.x; m < M_SUP; m += gridDim.x * blockDim.x) {
        float kl = e - A2[(long)n * M_SUP + m] + lse[m];
        lmin = fminf(lmin, kl);
        lmax = fmaxf(lmax, kl);
    }
    __shared__ unsigned smin, smax;
    if (threadIdx.x == 0) { smin = encf(INFINITY); smax = encf(-INFINITY); }
    __syncthreads();
    atomicMin(&smin, encf(lmin));
    atomicMax(&smax, encf(lmax));
    __syncthreads();
    if (threadIdx.x == 0) { atomicMin(&mm[0], smin); atomicMax(&mm[1], smax); }
}

__global__ void minmax_nk_k(const float* __restrict__ nk, unsigned* mm) {
    int n = blockIdx.y;
    float lmin = INFINITY, lmax = -INFINITY;
    for (int m = blockIdx.x * blockDim.x + threadIdx.x; m < M_SUP; m += gridDim.x * blockDim.x) {
        float v = nk[(long)n * M_SUP + m];
        lmin = fminf(lmin, v);
        lmax = fmaxf(lmax, v);
    }
    __shared__ unsigned smin, smax;
    if (threadIdx.x == 0) { smin = encf(INFINITY); smax = encf(-INFINITY); }
    __syncthreads();
    atomicMin(&smin, encf(lmin));
    atomicMax(&smax, encf(lmax));
    __syncthreads();
    if (threadIdx.x == 0) { atomicMin(&mm[2], smin); atomicMax(&mm[3], smax); }
}

__global__ __launch_bounds__(256) void final_k(
    const float* __restrict__ dot, const float* __restrict__ A2, const float* __restrict__ nk,
    const int* __restrict__ labels, const unsigned* __restrict__ mm,
    const float* __restrict__ ent, const float* __restrict__ lse, float* __restrict__ out)
{
    int n = blockIdx.x;
    __shared__ float bins[C_CLS];
    for (int c = threadIdx.x; c < C_CLS; c += 256) bins[c] = 0.f;
    __syncthreads();
    float klmin = decf(mm[0]), klmax = decf(mm[1]);
    float nkmin = decf(mm[2]), nkmax = decf(mm[3]);
    float ratio = (nkmax - nkmin) / (klmax - klmin);
    float e = ent[n];
    for (int m = threadIdx.x; m < M_SUP; m += 256) {
        float a2 = A2[(long)n * M_SUP + m];
        float v  = nk[(long)n * M_SUP + m];
        float kl = e - a2 + lse[m];
        float y  = (kl - klmin) * ratio + nkmin;
        float contrib = -GAMMA_F * y + ALPHA_F * expf(BETA_F * (v - 1.0f));
        atomicAdd(&bins[labels[m]], contrib);
    }
    __syncthreads();
    for (int c = threadIdx.x; c < C_CLS; c += 256)
        out[(long)n * C_CLS + c] = 100.f * dot[(long)n * C_PAD + c] + bins[c];
}

// ---------- launch ----------
extern "C" void kernel_launch(void* const* d_in, const int* in_sizes, int n_in,
                              void* d_out, int out_size, void* d_ws, size_t ws_size,
                              hipStream_t stream) {
    const float* image_features = (const float*)d_in[0];   // [N, D]
    const float* text_embeds    = (const float*)d_in[1];   // [C, D]
    const float* support_feats  = (const float*)d_in[2];   // [D, M]
    const int*   support_labels = (const int*)d_in[3];     // [M]
    float* out = (float*)d_out;

    char* base = (char*)d_ws;
    size_t off = 0;
    auto alloc = [&](size_t bytes) {
        void* p = base + off;
        off = (off + bytes + 255) & ~(size_t)255;
        return p;
    };
    short* Tnb  = (short*)alloc(sizeof(short) * C_CLS * D_DIM);   // normalized text bf16 [C, D]
    short* imgb = (short*)alloc(sizeof(short) * N_IMG * D_DIM);   // normalized image bf16 [N, D]
    short* Sb   = (short*)alloc(sizeof(short) * M_SUP * D_DIM);   // support^T bf16 [M, D]
    short* tb   = (short*)alloc(sizeof(short) * M_SUP * C_PAD);   // train logits bf16 [M, 1024]
    short* pb   = (short*)alloc(sizeof(short) * N_IMG * C_PAD);   // test probs bf16 [N, 1024]
    float* dot  = (float*)alloc(sizeof(float) * N_IMG * C_PAD);   // img @ Tn^T fp32 [N, 1024]
    float* lse  = (float*)alloc(sizeof(float) * M_SUP);
    float* ent  = (float*)alloc(sizeof(float) * N_IMG);
    float* A2   = (float*)alloc(sizeof(float) * N_IMG * M_SUP);   // p @ t^T
    float* nk   = (float*)alloc(sizeof(float) * N_IMG * M_SUP);   // img @ S
    unsigned* mm = (unsigned*)alloc(256);

    init_mm_k<<<1, 1, 0, stream>>>(mm);
    normalize_rows_k<<<C_CLS, 256, 0, stream>>>(text_embeds, Tnb);
    normalize_rows_k<<<N_IMG, 256, 0, stream>>>(image_features, imgb);
    transpose_bf16_k<<<dim3(M_SUP / 32, D_DIM / 32), 256, 0, stream>>>(support_feats, Sb);

    // GEMM1: tb[m,c] = 2 * Sb[m,:] . Tnb[c,:]   (I=M, J=C->1024 pad, K=D)
    mfma_gemm<true><<<dim3(8, 125), 256, 0, stream>>>(
        Sb, Tnb, tb, M_SUP, C_CLS, C_PAD, D_DIM, D_DIM, D_DIM, C_PAD, 2.0f);

    row_lse_k<<<M_SUP, 256, 0, stream>>>(tb, lse);

    // GEMM0: dot[n,c] = imgb[n,:] . Tnb[c,:]   (I=N, J=C, K=D)
    mfma_gemm<false><<<dim3(8, 4), 256, 0, stream>>>(
        imgb, Tnb, dot, N_IMG, C_CLS, C_PAD, D_DIM, D_DIM, D_DIM, C_PAD, 1.0f);

    test_softmax_k<<<N_IMG, 256, 0, stream>>>(dot, pb, ent);

    // GEMM2: A2[n,m] = pb[n,:] . tb[m,:]   (I=N, J=M, K=1024)
    mfma_gemm<false><<<dim3(125, 4), 256, 0, stream>>>(
        pb, tb, A2, N_IMG, M_SUP, M_SUP, C_PAD, C_PAD, C_PAD, M_SUP, 1.0f);

    // GEMM3: nk[n,m] = imgb[n,:] . Sb[m,:]   (I=N, J=M, K=D)
    mfma_gemm<false><<<dim3(125, 4), 256, 0, stream>>>(
        imgb, Sb, nk, N_IMG, M_SUP, M_SUP, D_DIM, D_DIM, D_DIM, M_SUP, 1.0f);

    minmax_kl_k<<<dim3(8, N_IMG), 256, 0, stream>>>(A2, ent, lse, mm);
    minmax_nk_k<<<dim3(8, N_IMG), 256, 0, stream>>>(nk, mm);

    final_k<<<N_IMG, 256, 0, stream>>>(dot, A2, nk, support_labels, mm, ent, lse, out);
}

// Round 3
// 292.176 us; speedup vs baseline: 4.5508x; 1.5109x over previous
//
#include <hip/hip_runtime.h>
#include <math.h>

#define TEMP_F   0.5f
#define ALPHA_F  1.0f
#define BETA_F   5.5f
#define GAMMA_F  5.0f
#define N_IMG    400
#define D_DIM    512
#define C_CLS    1000
#define C_PAD    1024
#define M_SUP    16000

typedef __attribute__((ext_vector_type(8))) short short8;
typedef __attribute__((ext_vector_type(4))) float f32x4;

// ---------- helpers ----------
__device__ __forceinline__ short f2bf(float f) {
    unsigned u = __float_as_uint(f);
    unsigned r = (u + 0x7fffu + ((u >> 16) & 1u)) >> 16;
    return (short)r;
}
__device__ __forceinline__ float bf2f(short s) {
    return __uint_as_float(((unsigned)(unsigned short)s) << 16);
}
__device__ __forceinline__ unsigned encf(float f) {
    unsigned u = __float_as_uint(f);
    return (u & 0x80000000u) ? ~u : (u | 0x80000000u);
}
__device__ __forceinline__ float decf(unsigned u) {
    return (u & 0x80000000u) ? __uint_as_float(u & 0x7FFFFFFFu) : __uint_as_float(~u);
}

__device__ __forceinline__ float block_reduce_sum(float v) {
    __shared__ float red[4];
    #pragma unroll
    for (int o = 32; o > 0; o >>= 1) v += __shfl_down(v, o, 64);
    int w = threadIdx.x >> 6, l = threadIdx.x & 63;
    __syncthreads();
    if (l == 0) red[w] = v;
    __syncthreads();
    float r = red[0];
    int nw = blockDim.x >> 6;
    for (int i = 1; i < nw; ++i) r += red[i];
    return r;
}

__device__ __forceinline__ float block_reduce_max(float v) {
    __shared__ float redm[4];
    #pragma unroll
    for (int o = 32; o > 0; o >>= 1) v = fmaxf(v, __shfl_down(v, o, 64));
    int w = threadIdx.x >> 6, l = threadIdx.x & 63;
    __syncthreads();
    if (l == 0) redm[w] = v;
    __syncthreads();
    float r = redm[0];
    int nw = blockDim.x >> 6;
    for (int i = 1; i < nw; ++i) r = fmaxf(r, redm[i]);
    return r;
}

__device__ __forceinline__ void gload_lds16(const void* g, void* l) {
    __builtin_amdgcn_global_load_lds(
        (const __attribute__((address_space(1))) unsigned int*)g,
        (__attribute__((address_space(3))) unsigned int*)l, 16, 0, 0);
}

// ---------- kernels ----------
__global__ void init_mm_k(unsigned* mm) {
    mm[0] = encf(INFINITY);   // klmin
    mm[1] = encf(-INFINITY);  // klmax
    mm[2] = encf(INFINITY);   // nkmin
    mm[3] = encf(-INFINITY);  // nkmax
}

// normalize rows of src [rows x 512] fp32 -> dst bf16 [rows x 512]
__global__ void normalize_rows_k(const float* __restrict__ src, short* __restrict__ dst) {
    int row = blockIdx.x;
    const float* s = src + (long)row * D_DIM;
    short* d = dst + (long)row * D_DIM;
    float ss = 0.f;
    for (int c = threadIdx.x; c < D_DIM; c += blockDim.x) { float v = s[c]; ss += v * v; }
    float tot = block_reduce_sum(ss);
    float inv = 1.0f / fmaxf(sqrtf(tot), 1e-12f);
    for (int c = threadIdx.x; c < D_DIM; c += blockDim.x) d[c] = f2bf(s[c] * inv);
}

// S [D_DIM x M_SUP] fp32 -> Sb [M_SUP x D_DIM] bf16
__global__ void transpose_bf16_k(const float* __restrict__ S, short* __restrict__ Sb) {
    __shared__ float tile[32][33];
    int m0 = blockIdx.x * 32, d0 = blockIdx.y * 32;
    int tx = threadIdx.x & 31, ty = threadIdx.x >> 5;  // 32 x 8
    #pragma unroll
    for (int r = 0; r < 32; r += 8)
        tile[ty + r][tx] = S[(long)(d0 + ty + r) * M_SUP + m0 + tx];
    __syncthreads();
    #pragma unroll
    for (int r = 0; r < 32; r += 8)
        Sb[(long)(m0 + ty + r) * D_DIM + d0 + tx] = f2bf(tile[tx][ty + r]);
}

// bf16 MFMA GEMM: C[i,j] = alpha * sum_k A[i,k]*B[j,k]
// 128x128 tile, BK=32, 256 threads (4 waves), 4x4 16x16x32 MFMAs per wave.
// EPI: 0 = fp32 store, 1 = bf16 store,
//      2 = kl-transform (v = ent[i] - v + lse[j]) fp32 store + minmax -> mm[0..1]
//      3 = fp32 store + minmax -> mm[2..3]
template<int EPI>
__global__ __launch_bounds__(256) void mfma_gemm(
    const short* __restrict__ A, const short* __restrict__ B, void* __restrict__ Cm,
    int I, int Jclamp, int Jout, int K, long lda, long ldb, long ldc, float alpha,
    const float* __restrict__ ent, const float* __restrict__ lse, unsigned* __restrict__ mm)
{
    __shared__ short As[128 * 32];
    __shared__ short Bs[128 * 32];
    const int tid = threadIdx.x;
    const int wave = tid >> 6;
    const int lane = tid & 63;
    const int i0 = blockIdx.y * 128;
    const int j0 = blockIdx.x * 128;

    const int srow = wave * 16 + (lane >> 2);  // staging row within 64-row group
    const int skk  = (lane & 3) * 8;           // staging k offset (bf16 elems)

    const int wm = (wave & 1) * 64;
    const int wn = (wave >> 1) * 64;
    const int fr = lane & 15;   // fragment row/col
    const int fq = lane >> 4;   // quad

    f32x4 acc[4][4] = {};

    for (int k0 = 0; k0 < K; k0 += 32) {
        #pragma unroll
        for (int q = 0; q < 2; ++q) {
            int gi = i0 + q * 64 + srow; if (gi > I - 1) gi = I - 1;
            gload_lds16(A + (long)gi * lda + k0 + skk, As + q * 2048 + wave * 512);
        }
        #pragma unroll
        for (int q = 0; q < 2; ++q) {
            int gj = j0 + q * 64 + srow; if (gj > Jclamp - 1) gj = Jclamp - 1;
            gload_lds16(B + (long)gj * ldb + k0 + skk, Bs + q * 2048 + wave * 512);
        }
        __syncthreads();

        short8 af[4], bf[4];
        #pragma unroll
        for (int mi = 0; mi < 4; ++mi)
            af[mi] = *(const short8*)(As + (wm + mi * 16 + fr) * 32 + fq * 8);
        #pragma unroll
        for (int ni = 0; ni < 4; ++ni)
            bf[ni] = *(const short8*)(Bs + (wn + ni * 16 + fr) * 32 + fq * 8);
        #pragma unroll
        for (int mi = 0; mi < 4; ++mi)
            #pragma unroll
            for (int ni = 0; ni < 4; ++ni)
                acc[mi][ni] = __builtin_amdgcn_mfma_f32_16x16x32_bf16(
                    af[mi], bf[ni], acc[mi][ni], 0, 0, 0);
        __syncthreads();
    }

    float lmin = INFINITY, lmax = -INFINITY;

    #pragma unroll
    for (int mi = 0; mi < 4; ++mi) {
        #pragma unroll
        for (int ni = 0; ni < 4; ++ni) {
            int gj = j0 + wn + ni * 16 + fr;
            float lsev = 0.f;
            if (EPI == 2) lsev = lse[gj < Jout ? gj : (Jout - 1)];
            #pragma unroll
            for (int t = 0; t < 4; ++t) {
                int gi = i0 + wm + mi * 16 + fq * 4 + t;
                float v = alpha * acc[mi][ni][t];
                if (EPI == 2) {
                    int gic = gi < I ? gi : (I - 1);
                    v = ent[gic] - v + lsev;
                }
                if (EPI >= 2) { lmin = fminf(lmin, v); lmax = fmaxf(lmax, v); }
                if (gi < I && gj < Jout) {
                    if (EPI == 1) ((short*)Cm)[(long)gi * ldc + gj] = f2bf(v);
                    else          ((float*)Cm)[(long)gi * ldc + gj] = v;
                }
            }
        }
    }

    if (EPI >= 2) {
        #pragma unroll
        for (int o = 32; o > 0; o >>= 1) {
            lmin = fminf(lmin, __shfl_down(lmin, o, 64));
            lmax = fmaxf(lmax, __shfl_down(lmax, o, 64));
        }
        __shared__ float rmin[4], rmax[4];
        if (lane == 0) { rmin[wave] = lmin; rmax[wave] = lmax; }
        __syncthreads();
        if (tid == 0) {
            float bmin = fminf(fminf(rmin[0], rmin[1]), fminf(rmin[2], rmin[3]));
            float bmax = fmaxf(fmaxf(rmax[0], rmax[1]), fmaxf(rmax[2], rmax[3]));
            int base = (EPI == 2) ? 0 : 2;
            atomicMin(&mm[base + 0], encf(bmin));
            atomicMax(&mm[base + 1], encf(bmax));
        }
    }
}

// per-row logsumexp over tb bf16 [M_SUP x C_PAD], cols < C_CLS
__global__ void row_lse_k(const short* __restrict__ t, float* __restrict__ lse) {
    int row = blockIdx.x;
    const short* r = t + (long)row * C_PAD;
    float mx = -INFINITY;
    for (int c = threadIdx.x; c < C_CLS; c += blockDim.x) mx = fmaxf(mx, bf2f(r[c]));
    mx = block_reduce_max(mx);
    float se = 0.f;
    for (int c = threadIdx.x; c < C_CLS; c += blockDim.x) se += expf(bf2f(r[c]) - mx);
    se = block_reduce_sum(se);
    if (threadIdx.x == 0) lse[row] = mx + logf(se);
}

// test softmax: logits = 2*dot; writes p as bf16 (pad zeros), entropy
__global__ void test_softmax_k(const float* __restrict__ dot, short* __restrict__ p,
                               float* __restrict__ ent) {
    int n = blockIdx.x;
    const float* dr = dot + (long)n * C_PAD;
    short* pr = p + (long)n * C_PAD;
    float mx = -INFINITY;
    for (int c = threadIdx.x; c < C_CLS; c += blockDim.x) mx = fmaxf(mx, 2.f * dr[c]);
    mx = block_reduce_max(mx);
    float se = 0.f;
    for (int c = threadIdx.x; c < C_CLS; c += blockDim.x) se += expf(2.f * dr[c] - mx);
    se = block_reduce_sum(se);
    float logsum = mx + logf(se);
    float e = 0.f;
    for (int c = threadIdx.x; c < C_PAD; c += blockDim.x) {
        if (c < C_CLS) {
            float lp = 2.f * dr[c] - logsum;
            float pv = expf(lp);
            pr[c] = f2bf(pv);
            e += pv * lp;
        } else {
            pr[c] = 0;
        }
    }
    e = block_reduce_sum(e);
    if (threadIdx.x == 0) ent[n] = e;
}

__global__ __launch_bounds__(256) void final_k(
    const float* __restrict__ dot, const float* __restrict__ kl, const float* __restrict__ nk,
    const int* __restrict__ labels, const unsigned* __restrict__ mm, float* __restrict__ out)
{
    int n = blockIdx.x;
    __shared__ float bins[C_CLS];
    for (int c = threadIdx.x; c < C_CLS; c += 256) bins[c] = 0.f;
    __syncthreads();
    float klmin = decf(mm[0]), klmax = decf(mm[1]);
    float nkmin = decf(mm[2]), nkmax = decf(mm[3]);
    float ratio = (nkmax - nkmin) / (klmax - klmin);
    for (int m = threadIdx.x; m < M_SUP; m += 256) {
        float klv = kl[(long)n * M_SUP + m];
        float v   = nk[(long)n * M_SUP + m];
        float y   = (klv - klmin) * ratio + nkmin;
        float contrib = -GAMMA_F * y + ALPHA_F * expf(BETA_F * (v - 1.0f));
        atomicAdd(&bins[labels[m]], contrib);
    }
    __syncthreads();
    for (int c = threadIdx.x; c < C_CLS; c += 256)
        out[(long)n * C_CLS + c] = 100.f * dot[(long)n * C_PAD + c] + bins[c];
}

// ---------- launch ----------
extern "C" void kernel_launch(void* const* d_in, const int* in_sizes, int n_in,
                              void* d_out, int out_size, void* d_ws, size_t ws_size,
                              hipStream_t stream) {
    const float* image_features = (const float*)d_in[0];   // [N, D]
    const float* text_embeds    = (const float*)d_in[1];   // [C, D]
    const float* support_feats  = (const float*)d_in[2];   // [D, M]
    const int*   support_labels = (const int*)d_in[3];     // [M]
    float* out = (float*)d_out;

    char* base = (char*)d_ws;
    size_t off = 0;
    auto alloc = [&](size_t bytes) {
        void* p = base + off;
        off = (off + bytes + 255) & ~(size_t)255;
        return p;
    };
    short* Tnb  = (short*)alloc(sizeof(short) * C_CLS * D_DIM);   // normalized text bf16 [C, D]
    short* imgb = (short*)alloc(sizeof(short) * N_IMG * D_DIM);   // normalized image bf16 [N, D]
    short* Sb   = (short*)alloc(sizeof(short) * M_SUP * D_DIM);   // support^T bf16 [M, D]
    short* tb   = (short*)alloc(sizeof(short) * M_SUP * C_PAD);   // train logits bf16 [M, 1024]
    short* pb   = (short*)alloc(sizeof(short) * N_IMG * C_PAD);   // test probs bf16 [N, 1024]
    float* dot  = (float*)alloc(sizeof(float) * N_IMG * C_PAD);   // img @ Tn^T fp32 [N, 1024]
    float* lse  = (float*)alloc(sizeof(float) * M_SUP);
    float* ent  = (float*)alloc(sizeof(float) * N_IMG);
    float* kl   = (float*)alloc(sizeof(float) * N_IMG * M_SUP);   // KL divergences
    float* nk   = (float*)alloc(sizeof(float) * N_IMG * M_SUP);   // img @ S
    unsigned* mm = (unsigned*)alloc(256);

    init_mm_k<<<1, 1, 0, stream>>>(mm);
    normalize_rows_k<<<C_CLS, 256, 0, stream>>>(text_embeds, Tnb);
    normalize_rows_k<<<N_IMG, 256, 0, stream>>>(image_features, imgb);
    transpose_bf16_k<<<dim3(M_SUP / 32, D_DIM / 32), 256, 0, stream>>>(support_feats, Sb);

    // GEMM1: tb[m,c] = 2 * Sb[m,:] . Tnb[c,:]   (I=M, J=C->1024 pad, K=D)
    mfma_gemm<1><<<dim3(8, 125), 256, 0, stream>>>(
        Sb, Tnb, tb, M_SUP, C_CLS, C_PAD, D_DIM, D_DIM, D_DIM, C_PAD, 2.0f,
        nullptr, nullptr, nullptr);

    row_lse_k<<<M_SUP, 256, 0, stream>>>(tb, lse);

    // GEMM0: dot[n,c] = imgb[n,:] . Tnb[c,:]   (I=N, J=C, K=D)
    mfma_gemm<0><<<dim3(8, 4), 256, 0, stream>>>(
        imgb, Tnb, dot, N_IMG, C_CLS, C_PAD, D_DIM, D_DIM, D_DIM, C_PAD, 1.0f,
        nullptr, nullptr, nullptr);

    test_softmax_k<<<N_IMG, 256, 0, stream>>>(dot, pb, ent);

    // GEMM2 + KL epilogue + minmax: kl[n,m] = ent[n] - pb[n,:].tb[m,:] + lse[m]
    mfma_gemm<2><<<dim3(125, 4), 256, 0, stream>>>(
        pb, tb, kl, N_IMG, M_SUP, M_SUP, C_PAD, C_PAD, C_PAD, M_SUP, 1.0f,
        ent, lse, mm);

    // GEMM3 + minmax: nk[n,m] = imgb[n,:] . Sb[m,:]
    mfma_gemm<3><<<dim3(125, 4), 256, 0, stream>>>(
        imgb, Sb, nk, N_IMG, M_SUP, M_SUP, D_DIM, D_DIM, D_DIM, M_SUP, 1.0f,
        nullptr, nullptr, mm);

    final_k<<<N_IMG, 256, 0, stream>>>(dot, kl, nk, support_labels, mm, out);
}